// Round 1
// 282.413 us; speedup vs baseline: 1.0124x; 1.0124x over previous
//
#include <hip/hip_runtime.h>

// Reference collapses: softmax over a size-1 axis => weights == 1 => attn == v.
// out = chem_16 @ (Wo @ Wv)^T + (Wo @ bv + bo).  fp_16 / Wq / Wk are dead code.
// DIM=16, B=2097152.
//
// R1: coalesced layout. 4 consecutive lanes co-own one row (one float4 quarter
// each); quarters exchanged via __shfl_xor (quad-perm, stays in-wave).
// R2 (this round): single fused kernel. Each block redundantly folds the
// 16x16 collapsed weight (Wo@Wv) + bias into LDS (16 FMA/thread, one barrier,
// ~2KB weight reads/block = 16MB total, L2-broadcast) — removes the serialized
// 1-block pre-kernel (~3-4us of launch+drain in the graph). Global streams are
// touch-once, so loads/stores are non-temporal to stop L2/L3 allocation.

#define DIM 16
#define BATCH 2097152

typedef float f4 __attribute__((ext_vector_type(4)));

__device__ __forceinline__ f4 shfl_xor_f4(f4 v, int mask) {
    f4 r;
    r.x = __shfl_xor(v.x, mask, 64);
    r.y = __shfl_xor(v.y, mask, 64);
    r.z = __shfl_xor(v.z, mask, 64);
    r.w = __shfl_xor(v.w, mask, 64);
    return r;
}

// Lane t handles quarter q = t&3 of rows (blockIdx*256 + t/4 + 64k), k = 0..3.
// Global float4 index = blockIdx*1024 + 256k + t  (coalesced, 1KiB/wave/instr).
__global__ __launch_bounds__(256) void fused_affine(
    const float* __restrict__ x,
    const float* __restrict__ in_proj_weight,
    const float* __restrict__ in_proj_bias,
    const float* __restrict__ out_proj_weight,
    const float* __restrict__ out_proj_bias,
    float* __restrict__ out) {
    __shared__ __align__(16) float wfold[272];   // 256 weights + 16 bias

    const int t = threadIdx.x;

    // ---- per-block weight fold (replaces the old 1-block pre-kernel) ----
    // wfold[j*16+i] = Wc[j][i] = sum_k Wo[j][k] * Wv[k][i];  Wv = rows 32..47.
    {
        const int j = t >> 4;
        const int i = t & 15;
        float acc = 0.0f;
#pragma unroll
        for (int k = 0; k < 16; ++k)
            acc += out_proj_weight[j * 16 + k] * in_proj_weight[(32 + k) * 16 + i];
        wfold[t] = acc;
        if (t < 16) {
            float b = out_proj_bias[t];
#pragma unroll
            for (int k = 0; k < 16; ++k)
                b += out_proj_weight[t * 16 + k] * in_proj_bias[32 + k];
            wfold[256 + t] = b;
        }
    }
    __syncthreads();

    // ---- per-lane permuted weight block, LDS -> VGPR (once) ----
    // w[m][jp] = Wc[(q*4+jp)*16 + (q^m)*4 .. +3]. Addresses depend only on
    // q = t&3 => 4 distinct LDS addresses per ds_read_b128; 16-lane groups
    // share an address (broadcast, conflict-free).
    const int q = t & 3;
    f4 w[4][4];
#pragma unroll
    for (int m = 0; m < 4; ++m) {
        const int qc = q ^ m;
#pragma unroll
        for (int jp = 0; jp < 4; ++jp)
            w[m][jp] = *(const f4*)(wfold + (q * 4 + jp) * 16 + qc * 4);
    }
    const f4 bias = *(const f4*)(wfold + 256 + q * 4);

    const f4* xv = (const f4*)x;
    f4* ov = (f4*)out;
    const size_t base = (size_t)blockIdx.x * 1024;

#pragma unroll
    for (int k = 0; k < 4; ++k) {
        const size_t idx = base + (size_t)k * 256 + t;
        f4 xs0 = __builtin_nontemporal_load(xv + idx);  // own quarter q
        f4 xs1 = shfl_xor_f4(xs0, 1);                   // quarter q^1
        f4 xs2 = shfl_xor_f4(xs0, 2);                   // quarter q^2
        f4 xs3 = shfl_xor_f4(xs0, 3);                   // quarter q^3

        f4 acc = bias;
#define ACCUM(m, xsv)                                                   \
        acc.x += xsv.x * w[m][0].x + xsv.y * w[m][0].y +                \
                 xsv.z * w[m][0].z + xsv.w * w[m][0].w;                 \
        acc.y += xsv.x * w[m][1].x + xsv.y * w[m][1].y +                \
                 xsv.z * w[m][1].z + xsv.w * w[m][1].w;                 \
        acc.z += xsv.x * w[m][2].x + xsv.y * w[m][2].y +                \
                 xsv.z * w[m][2].z + xsv.w * w[m][2].w;                 \
        acc.w += xsv.x * w[m][3].x + xsv.y * w[m][3].y +                \
                 xsv.z * w[m][3].z + xsv.w * w[m][3].w;
        ACCUM(0, xs0)
        ACCUM(1, xs1)
        ACCUM(2, xs2)
        ACCUM(3, xs3)
#undef ACCUM

        __builtin_nontemporal_store(acc, ov + idx);     // coalesced store
    }
}

extern "C" void kernel_launch(void* const* d_in, const int* in_sizes, int n_in,
                              void* d_out, int out_size, void* d_ws, size_t ws_size,
                              hipStream_t stream) {
    // setup_inputs order: fp_16, chem_16, in_proj_weight, in_proj_bias,
    //                     out_proj_weight, out_proj_bias
    const float* chem        = (const float*)d_in[1];
    const float* in_proj_w   = (const float*)d_in[2];
    const float* in_proj_b   = (const float*)d_in[3];
    const float* out_proj_w  = (const float*)d_in[4];
    const float* out_proj_b  = (const float*)d_in[5];
    float* out = (float*)d_out;

    const int blocks = BATCH / 256;   // 8192, exact
    fused_affine<<<blocks, 256, 0, stream>>>(chem, in_proj_w, in_proj_b,
                                             out_proj_w, out_proj_b, out);
}